// Round 4
// baseline (113.581 us; speedup 1.0000x reference)
//
#include <hip/hip_runtime.h>
#include <climits>
#include <stdint.h>

typedef unsigned int u32;
typedef unsigned long long u64;
typedef int v4i __attribute__((ext_vector_type(4)));

#define HH 1536
#define WW 2048
#define NPIX (HH*WW)        // 3145728
#define WSHIFT 11
#define WPR 64              // 32-bit words per row
#define SH 8                // rows per strip (one wave per row)
#define NS 192              // strip blocks
#define NZ 192              // zero-writer blocks (heterogeneous grid)
#define NB (NS+NZ)          // total blocks in k_stripf grid = 384 (2/CU)
#define TPB 512             // threads per block (8 waves)
#define RPR 32              // run slots per row
#define SLOTS (SH*RPR)      // 256
#define NCAP 1024           // global node cap
#define BSLOT 8             // staged boundary-run slots per side
#define NZV4 (NPIX*5/4)     // v4i covering all of d_out (obb + oval) = 3932160
#define ZPB (NZV4/NZ)       // zero v4i per zero-block = 20480
#define ZIT (ZPB/TPB)       // zero iterations per thread = 40

#define GLD(p) __hip_atomic_load((p), __ATOMIC_RELAXED, __HIP_MEMORY_SCOPE_AGENT)

// ---------------- K1: threshold+pack only (4 px/thread), 48 waves/CU ---------
// Massively parallel (3072 blocks): BW-bound. R2 lesson: folding this into
// low-occupancy strip blocks makes it latency-bound at 20% BW. Keep separate.
__global__ void k_flags(const float4* __restrict__ xv4,
                        u64* __restrict__ combp64, u64* __restrict__ textp64,
                        int* __restrict__ ctrs) {
    int tid = blockIdx.x * 256 + threadIdx.x;
    int l = threadIdx.x & 63, wv = threadIdx.x >> 6;
    float4 a = xv4[tid * 2 + 0];   // px0=(x,y) px1=(z,w)
    float4 b = xv4[tid * 2 + 1];   // px2=(x,y) px3=(z,w)
    u32 nc = 0, nt = 0;
    { u32 tx = a.x > 0.4f, cb = tx | (a.y > 0.4f); nc |= cb;      nt |= tx; }
    { u32 tx = a.z > 0.4f, cb = tx | (a.w > 0.4f); nc |= cb << 1; nt |= tx << 1; }
    { u32 tx = b.x > 0.4f, cb = tx | (b.y > 0.4f); nc |= cb << 2; nt |= tx << 2; }
    { u32 tx = b.z > 0.4f, cb = tx | (b.w > 0.4f); nc |= cb << 3; nt |= tx << 3; }
    u64 vc = (u64)nc << (4 * (l & 15));
    u64 vt = (u64)nt << (4 * (l & 15));
    #pragma unroll
    for (int o = 1; o < 16; o <<= 1) {
        vc |= __shfl_xor(vc, o);
        vt |= __shfl_xor(vt, o);
    }
    if ((l & 15) == 0) {
        int w = blockIdx.x * 16 + wv * 4 + (l >> 4);
        combp64[w] = vc;
        textp64[w] = vt;
    }
    if (tid == 0) { ctrs[0] = 0; ctrs[1] = 0; }   // done, gcnt
}

// ---------------- LDS UF with path halving -----------------------------------
__device__ __forceinline__ int lfind_h(int* L, int x) {
    while (true) {
        int p = L[x];
        if (p == x) return x;
        int g = L[p];
        if (g == p) return p;
        L[x] = g;
        x = g;
    }
}

__device__ __forceinline__ void lmerge(int* L, int a, int b) {
    while (true) {
        a = lfind_h(L, a);
        b = lfind_h(L, b);
        if (a == b) return;
        if (a < b) { int s = a; a = b; b = s; }
        int old = atomicMin(&L[a], b);
        if (old == a) return;
        a = old;
    }
}

// ---------------- K2: heterogeneous grid — strips + zero-writers -------------
// R1/R3 lesson: zero-stores issued inside the barrier-synchronized strip code
// get drained by the NEXT __syncthreads (per-wave vmcnt(0) before s_barrier),
// serializing the 63 MB write in front of the strip phases. Fix: put the
// zeroing in DEDICATED blocks (blockIdx >= NS) that share no barrier with the
// strip blocks. All NB=384 blocks are co-resident (2/CU by LDS), so the
// BW-bound zero drain and the latency-bound UF pipeline truly overlap.
// The last-block election counts all NB blocks: every block's stores are
// drained (per-wave vmcnt(0) at its pre-election barrier) + release-fenced
// before the final block emits sparse obb/oval (ordering validated R1-R3).
// Encoded maxima (>0, LDS 0-init identity): 2047-row, row+1, 2048-start, end+1
__global__ __launch_bounds__(TPB) void k_stripf(
        const u32* __restrict__ combp, const u32* __restrict__ textp,
        u32* __restrict__ brun_se, int* __restrict__ brun_id,
        u64* __restrict__ bpack, int* __restrict__ bcnt,
        int* __restrict__ groots, int* __restrict__ ctrs,
        v4i* __restrict__ obb, int* __restrict__ oval) {
    __shared__ u32 sb[SH][RPR], eb[SH][RPR];
    __shared__ u32 rec[SLOTS];
    __shared__ int lab[SLOTS];
    __shared__ int a0[SLOTS], a1[SLOTS], a2[SLOTS], a3[SLOTS], atx[SLOTS];
    __shared__ int nodemap[SLOTS];
    __shared__ int nper[SH];
    __shared__ int wtot[8], woff[8];
    __shared__ int sBase, sLast;
    __shared__ u64 sbpk[NS * 2 * BSLOT];
    __shared__ int sbc[NS * 2];
    __shared__ int flab[NCAP];
    __shared__ int f0[NCAP], f1[NCAP], f2[NCAP], f3[NCAP], ftx2[NCAP], fpix[NCAP];

    int t = threadIdx.x;
    int wv = t >> 6, l = t & 63;

    if (blockIdx.x >= NS) {
        // ---- zero role: stream 1/NZ of d_out, no strip barriers -------------
        int zb = blockIdx.x - NS;
        v4i z = {0, 0, 0, 0};
        v4i* oz = obb + (size_t)zb * ZPB;
        #pragma unroll 8
        for (int k = 0; k < ZIT; ++k)
            oz[k * TPB + t] = z;
    } else {
        // ---- strip role: phases 1..7 (proven R0 pipeline, SH=8) -------------
        int strip = blockIdx.x;
        int rbase = strip * SH;

        // Phase 1: dilate + extract runs, ONE row per wave
        u32 tK;
        int nrW;
        {
            int lr = wv;
            int r = rbase + lr;
            int base = r * WPR + l;
            u32 c0 = combp[base];
            u32 cm = (r > 0)      ? combp[base - WPR] : 0u;
            u32 cp = (r < HH - 1) ? combp[base + WPR] : 0u;
            u32 v = c0 | cm | cp;
            u32 vl = __shfl_up(v, 1);   if (l == 0)  vl = 0;
            u32 vr = __shfl_down(v, 1); if (l == 63) vr = 0;
            u32 f = v | (v << 1) | (v >> 1) | (vl >> 31) | (vr << 31);
            u32 flw = __shfl_up(f, 1);   if (l == 0)  flw = 0;
            u32 frw = __shfl_down(f, 1); if (l == 63) frw = 0;
            u32 smask = f & ~((f << 1) | (flw >> 31));
            u32 emask = f & ~((f >> 1) | ((frw & 1u) << 31));
            int ns = __popc(smask), ne = __popc(emask);
            int is = ns, ie = ne;
            #pragma unroll
            for (int o = 1; o < 64; o <<= 1) {
                int a = __shfl_up(is, o); if (l >= o) is += a;
                int b = __shfl_up(ie, o); if (l >= o) ie += b;
            }
            int ks = is - ns, ke = ie - ne;
            u32 m = smask; int k = ks;
            while (m) { int b = __ffs(m) - 1; m &= m - 1; if (k < RPR) sb[wv][k] = (u32)(l * 32 + b); ++k; }
            m = emask; k = ke;
            while (m) { int b = __ffs(m) - 1; m &= m - 1; if (k < RPR) eb[wv][k] = (u32)(l * 32 + b); ++k; }
            nrW = min(__shfl(is, 63), RPR);
            tK = textp[base] & f;
            if (l == 0) nper[lr] = nrW;
        }
        if (t < SLOTS) {
            lab[t] = t; a0[t] = 0; a1[t] = 0; a2[t] = 0; a3[t] = 0; atx[t] = 0;
            nodemap[t] = -1;
        }
        __syncthreads();

        // Phase 2: per-run txt bit + rec build
        {
            int lr = wv;
            int nr = nrW;
            u32 txtm = 0;
            for (int kk = 0; kk < nr; ++kk) {
                int st = (int)sb[lr][kk], en = (int)eb[lr][kk];
                int lo = max(st - l * 32, 0), hi = min(en - l * 32, 31);
                u32 mask = 0;
                if (lo <= hi)
                    mask = ((hi == 31) ? 0xFFFFFFFFu : ((1u << (hi + 1)) - 1u)) & ~((1u << lo) - 1u);
                int any = __any((tK & mask) != 0);
                txtm |= (any ? 1u : 0u) << kk;
            }
            if (l < nr)
                rec[lr * RPR + l] = sb[lr][l] | (eb[lr][l] << 11) | (((txtm >> l) & 1u) << 22);
        }
        __syncthreads();

        // Phase 3: vertical merges (SH-1 row pairs, two-pointer, all LDS)
        if (t < SH - 1) {
            int na = nper[t], nb = nper[t + 1];
            int i = 0, j = 0;
            while (i < na && j < nb) {
                u32 ra = rec[t * RPR + i], rb = rec[(t + 1) * RPR + j];
                int sa = ra & 2047, ea = (ra >> 11) & 2047;
                int sb2 = rb & 2047, eb2 = (rb >> 11) & 2047;
                if (sa <= eb2 && sb2 <= ea) lmerge(lab, t * RPR + i, (t + 1) * RPR + j);
                if (ea <= eb2) ++i; else ++j;
            }
        }
        __syncthreads();

        // Phase 4: jump compression
        #pragma unroll
        for (int pass = 0; pass < 5; ++pass) {
            if (t < SLOTS) {
                int p = lab[t], g = lab[p];
                if (g != p) lab[t] = g;
            }
            __syncthreads();
        }

        // Phase 5: fold runs into strip-root accumulators (LDS atomics)
        int occ = (t < SLOTS) && ((t & (RPR - 1)) < nper[t >> 5]);
        if (occ) {
            u32 rc_ = rec[t];
            int st_ = rc_ & 2047, en_ = (rc_ >> 11) & 2047, tb = (int)((rc_ >> 22) & 1u);
            int r = rbase + (t >> 5);
            int root = lab[t];
            atomicMax(&a0[root], 2047 - r);
            atomicMax(&a1[root], r + 1);
            atomicMax(&a2[root], 2048 - st_);
            atomicMax(&a3[root], en_ + 1);
            if (tb) atomicOr(&atx[root], 1);
        }
        __syncthreads();

        // Phase 6: allocate global node ids, write root records (stride 8)
        int flag = occ && (lab[t] == t);
        u64 bmask = __ballot(flag);
        int lanepfx = __popcll(bmask & ((1ull << l) - 1ull));
        if (l == 0) wtot[wv] = __popcll(bmask);
        __syncthreads();
        if (t == 0) {
            int s = 0;
            for (int w2 = 0; w2 < 8; ++w2) { woff[w2] = s; s += wtot[w2]; }
            sBase = atomicAdd(&ctrs[1], s);
        }
        __syncthreads();
        if (flag) {
            int node = sBase + woff[wv] + lanepfx;
            if (node < NCAP) {
                nodemap[t] = node;
                int g = node * 8;
                int r = rbase + (t >> 5);
                groots[g + 0] = a0[t];
                groots[g + 1] = a1[t];
                groots[g + 2] = a2[t];
                groots[g + 3] = a3[t];
                groots[g + 4] = atx[t];
                groots[g + 5] = (r << WSHIFT) | (int)(rec[t] & 2047);
            }
        }
        __syncthreads();

        // Phase 7: emit boundary runs: packed contiguous + full fallback
        if (t < SLOTS) {
            int lr = t >> 5, k = t & (RPR - 1);
            if ((lr == 0 || lr == SH - 1) && k < nper[lr]) {
                int side = (lr == 0) ? 0 : 1;
                int id = nodemap[lab[t]];
                if (k < BSLOT)
                    bpack[(strip * 2 + side) * BSLOT + k] =
                        (u64)rec[t] | ((u64)(u32)(id + 1) << 32);
                int o = (strip * 2 + side) * RPR + k;
                brun_se[o] = rec[t];
                brun_id[o] = id;
            }
        }
        if (t == 0) {
            bcnt[strip * 2 + 0] = nper[0];
            bcnt[strip * 2 + 1] = nper[SH - 1];
        }
    }
    __syncthreads();   // both roles: per-wave vmcnt(0) drains all global stores

    // ---- last-block election over ALL NB blocks: release fence + ACQ_REL ---
    if (t == 0) {
        __threadfence();
        int old = __hip_atomic_fetch_add(&ctrs[0], 1, __ATOMIC_ACQ_REL,
                                         __HIP_MEMORY_SCOPE_AGENT);
        sLast = (old == NB - 1);
    }
    __syncthreads();
    if (!sLast) return;

    // ================= FINAL PHASE (last block; plain pipelined loads) =======
    int ncnt = min(ctrs[1], NCAP);
    for (int n = t; n < ncnt; n += TPB) {
        flab[n] = n; f0[n] = 0; f1[n] = 0; f2[n] = 0; f3[n] = 0;
        ftx2[n] = 0; fpix[n] = INT_MAX;
    }
    for (int s = t; s < NS * 2; s += TPB) sbc[s] = bcnt[s];
    for (int u = t; u < NS * 2 * BSLOT; u += TPB) sbpk[u] = bpack[u];
    __syncthreads();

    // joins: strip b last row vs strip b+1 first row
    if (t < NS - 1) {
        int A = t * 2 + 1, B = (t + 1) * 2;
        int na = sbc[A], nb = sbc[B];
        if (na <= BSLOT && nb <= BSLOT) {
            int i = 0, j = 0;
            while (i < na && j < nb) {
                u64 pa = sbpk[A * BSLOT + i], pb = sbpk[B * BSLOT + j];
                u32 ra = (u32)pa, rb = (u32)pb;
                int sa = ra & 2047, ea = (ra >> 11) & 2047;
                int sb2 = rb & 2047, eb2 = (rb >> 11) & 2047;
                if (sa <= eb2 && sb2 <= ea) {
                    int ia = (int)(pa >> 32) - 1, ib = (int)(pb >> 32) - 1;
                    if (ia >= 0 && ib >= 0) lmerge(flab, ia, ib);
                }
                if (ea <= eb2) ++i; else ++j;
            }
        } else {   // rare fallback: full arrays via agent-scope loads
            int i = 0, j = 0;
            while (i < na && j < nb) {
                u32 ra = GLD(&brun_se[A * RPR + i]), rb = GLD(&brun_se[B * RPR + j]);
                int sa = ra & 2047, ea = (ra >> 11) & 2047;
                int sb2 = rb & 2047, eb2 = (rb >> 11) & 2047;
                if (sa <= eb2 && sb2 <= ea) {
                    int ia = GLD(&brun_id[A * RPR + i]), ib = GLD(&brun_id[B * RPR + j]);
                    if (ia >= 0 && ib >= 0) lmerge(flab, ia, ib);
                }
                if (ea <= eb2) ++i; else ++j;
            }
        }
    }
    __syncthreads();

    #pragma unroll
    for (int pass = 0; pass < 6; ++pass) {     // jump compression
        for (int n = t; n < ncnt; n += TPB) {
            int p = flab[n], g = flab[p];
            if (g != p) flab[n] = g;
        }
        __syncthreads();
    }

    // fold root records: two dwordx4 plain loads per node, LDS atomics
    for (int n = t; n < ncnt; n += TPB) {
        int R = flab[n];
        v4i lo = *(const v4i*)&groots[n * 8];
        v4i hi = *(const v4i*)&groots[n * 8 + 4];
        atomicMax(&f0[R], lo.x);
        atomicMax(&f1[R], lo.y);
        atomicMax(&f2[R], lo.z);
        atomicMax(&f3[R], lo.w);
        if (hi.x) atomicOr(&ftx2[R], 1);
        atomicMin(&fpix[R], hi.y);
    }
    __syncthreads();

    // emit valid final roots into the zero-block-cleared d_out
    for (int n = t; n < ncnt; n += TPB) {
        if (flab[n] == n) {
            int ym = 2047 - f0[n], yx = f1[n] - 1;
            int xm = 2048 - f2[n], xx = f3[n] - 1;
            int h = yx - ym, w = xx - xm;
            if (h > 4 && w > 4 && ftx2[n]) {
                int p = fpix[n];
                v4i bb = {ym, xm, h, w};
                obb[p] = bb;
                oval[p] = 1;
            }
        }
    }
}

extern "C" void kernel_launch(void* const* d_in, const int* in_sizes, int n_in,
                              void* d_out, int out_size, void* d_ws, size_t ws_size,
                              hipStream_t stream) {
    const float* x = (const float*)d_in[0];

    // ws layout (alignment: groots 16B, bpack 8B)
    u32* combp   = (u32*)d_ws;                     // NPIX/32 words
    u32* textp   = combp + NPIX / 32;              // NPIX/32
    int* groots  = (int*)(textp + NPIX / 32);      // NCAP*8 (16B-aligned)
    u64* bpack   = (u64*)(groots + NCAP * 8);      // NS*2*BSLOT (8B-aligned)
    u32* brun_se = (u32*)(bpack + NS * 2 * BSLOT); // NS*2*RPR
    int* brun_id = (int*)(brun_se + NS * 2 * RPR); // NS*2*RPR
    int* bcnt    = brun_id + NS * 2 * RPR;         // NS*2
    int* ctrs    = bcnt + NS * 2;                  // [0]=done [1]=gcnt

    int* obb  = (int*)d_out;
    int* oval = obb + (size_t)NPIX * 4;

    k_flags<<<NPIX / 4 / 256, 256, 0, stream>>>((const float4*)x, (u64*)combp,
                                                (u64*)textp, ctrs);
    k_stripf<<<NB, TPB, 0, stream>>>(combp, textp, brun_se, brun_id, bpack,
                                     bcnt, groots, ctrs, (v4i*)obb, oval);
}

// Round 5
// 108.716 us; speedup vs baseline: 1.0448x; 1.0448x over previous
//
#include <hip/hip_runtime.h>
#include <climits>
#include <stdint.h>

typedef unsigned int u32;
typedef unsigned long long u64;
typedef int v4i __attribute__((ext_vector_type(4)));

#define HH 1536
#define WW 2048
#define NPIX (HH*WW)        // 3145728
#define WSHIFT 11
#define WPR 64              // 32-bit words per row
#define SH 8                // rows per strip (one wave per row)
#define NS 192              // strips
#define RPR 32              // run slots per row
#define SLOTS (SH*RPR)      // 256
#define NCAP 1024           // global node cap (~300 expected)
#define BSLOT 8             // staged boundary-run slots per side
#define NTH (NPIX/4)        // k_flags threads = 786432

#define GLD(p) __hip_atomic_load((p), __ATOMIC_RELAXED, __HIP_MEMORY_SCOPE_AGENT)

// ---------------- K1: threshold+pack (4 px/thread) AND zero d_out ------------
// R0 structure, restored after R1-R4 ablations all regressed:
//  - zeroing must live in THIS 3072-block kernel (12288 waves keep the 63 MB
//    store stream at ~6 TB/s; 256-block variants cap at 1.4-3 TB/s — R3/R4)
//  - fusing the x-read into strip blocks makes it latency-bound at 20% BW (R2)
//  - zero-stores inside barrier-synchronized strip code get drained by the
//    next __syncthreads' vmcnt(0), serializing them (R1/R3)
// This kernel moves 89.7 MB in ~15 us = ~95% of achievable HBM BW: roofline.
__global__ void k_flags(const float4* __restrict__ xv4,
                        u64* __restrict__ combp64, u64* __restrict__ textp64,
                        v4i* __restrict__ out4, int* __restrict__ ctrs) {
    int tid = blockIdx.x * 256 + threadIdx.x;
    int l = threadIdx.x & 63, wv = threadIdx.x >> 6;
    float4 a = xv4[tid * 2 + 0];   // px0=(x,y) px1=(z,w)
    float4 b = xv4[tid * 2 + 1];   // px2=(x,y) px3=(z,w)
    u32 nc = 0, nt = 0;
    { u32 tx = a.x > 0.4f, cb = tx | (a.y > 0.4f); nc |= cb;      nt |= tx; }
    { u32 tx = a.z > 0.4f, cb = tx | (a.w > 0.4f); nc |= cb << 1; nt |= tx << 1; }
    { u32 tx = b.x > 0.4f, cb = tx | (b.y > 0.4f); nc |= cb << 2; nt |= tx << 2; }
    { u32 tx = b.z > 0.4f, cb = tx | (b.w > 0.4f); nc |= cb << 3; nt |= tx << 3; }
    u64 vc = (u64)nc << (4 * (l & 15));
    u64 vt = (u64)nt << (4 * (l & 15));
    #pragma unroll
    for (int o = 1; o < 16; o <<= 1) {
        vc |= __shfl_xor(vc, o);
        vt |= __shfl_xor(vt, o);
    }
    if ((l & 15) == 0) {
        int w = blockIdx.x * 16 + wv * 4 + (l >> 4);
        combp64[w] = vc;
        textp64[w] = vt;
    }
    v4i z = {0, 0, 0, 0};
    #pragma unroll
    for (int k = 0; k < 5; ++k)
        out4[tid + k * NTH] = z;
    if (tid == 0) { ctrs[0] = 0; ctrs[1] = 0; }   // done, gcnt
}

// ---------------- LDS UF with path halving -----------------------------------
__device__ __forceinline__ int lfind_h(int* L, int x) {
    while (true) {
        int p = L[x];
        if (p == x) return x;
        int g = L[p];
        if (g == p) return p;
        L[x] = g;
        x = g;
    }
}

__device__ __forceinline__ void lmerge(int* L, int a, int b) {
    while (true) {
        a = lfind_h(L, a);
        b = lfind_h(L, b);
        if (a == b) return;
        if (a < b) { int s = a; a = b; b = s; }
        int old = atomicMin(&L[a], b);
        if (old == a) return;
        a = old;
    }
}

// ---------------- K2: 8-row strips (192 blocks, 1 wave/row) + staged final ---
// Encoded maxima (>0, LDS 0-init identity): 2047-row, row+1, 2048-start, end+1
__global__ __launch_bounds__(512) void k_stripf(
        const u32* __restrict__ combp, const u32* __restrict__ textp,
        u32* __restrict__ brun_se, int* __restrict__ brun_id,
        u64* __restrict__ bpack, int* __restrict__ bcnt,
        int* __restrict__ groots, int* __restrict__ ctrs,
        v4i* __restrict__ obb, int* __restrict__ oval) {
    __shared__ u32 sb[SH][RPR], eb[SH][RPR];
    __shared__ u32 rec[SLOTS];
    __shared__ int lab[SLOTS];
    __shared__ int a0[SLOTS], a1[SLOTS], a2[SLOTS], a3[SLOTS], atx[SLOTS];
    __shared__ int nodemap[SLOTS];
    __shared__ int nper[SH];
    __shared__ int wtot[8], woff[8];
    __shared__ int sBase, sLast;
    __shared__ u64 sbpk[NS * 2 * BSLOT];
    __shared__ int sbc[NS * 2];
    __shared__ int flab[NCAP];
    __shared__ int f0[NCAP], f1[NCAP], f2[NCAP], f3[NCAP], ftx2[NCAP], fpix[NCAP];

    int strip = blockIdx.x;
    int rbase = strip * SH;
    int t = threadIdx.x;
    int wv = t >> 6, l = t & 63;

    // ---- Phase 1: dilate + extract runs, ONE row per wave ----
    u32 tK;
    int nrW;
    {
        int lr = wv;
        int r = rbase + lr;
        int base = r * WPR + l;
        u32 c0 = combp[base];
        u32 cm = (r > 0)      ? combp[base - WPR] : 0u;
        u32 cp = (r < HH - 1) ? combp[base + WPR] : 0u;
        u32 v = c0 | cm | cp;
        u32 vl = __shfl_up(v, 1);   if (l == 0)  vl = 0;
        u32 vr = __shfl_down(v, 1); if (l == 63) vr = 0;
        u32 f = v | (v << 1) | (v >> 1) | (vl >> 31) | (vr << 31);
        u32 flw = __shfl_up(f, 1);   if (l == 0)  flw = 0;
        u32 frw = __shfl_down(f, 1); if (l == 63) frw = 0;
        u32 smask = f & ~((f << 1) | (flw >> 31));
        u32 emask = f & ~((f >> 1) | ((frw & 1u) << 31));
        int ns = __popc(smask), ne = __popc(emask);
        int is = ns, ie = ne;
        #pragma unroll
        for (int o = 1; o < 64; o <<= 1) {
            int a = __shfl_up(is, o); if (l >= o) is += a;
            int b = __shfl_up(ie, o); if (l >= o) ie += b;
        }
        int ks = is - ns, ke = ie - ne;
        u32 m = smask; int k = ks;
        while (m) { int b = __ffs(m) - 1; m &= m - 1; if (k < RPR) sb[lr][k] = (u32)(l * 32 + b); ++k; }
        m = emask; k = ke;
        while (m) { int b = __ffs(m) - 1; m &= m - 1; if (k < RPR) eb[lr][k] = (u32)(l * 32 + b); ++k; }
        nrW = min(__shfl(is, 63), RPR);
        tK = textp[base] & f;
        if (l == 0) nper[lr] = nrW;
    }
    if (t < SLOTS) {
        lab[t] = t; a0[t] = 0; a1[t] = 0; a2[t] = 0; a3[t] = 0; atx[t] = 0;
        nodemap[t] = -1;
    }
    __syncthreads();

    // ---- Phase 2: per-run txt bit + rec build ----
    {
        int lr = wv;
        int nr = nrW;
        u32 txtm = 0;
        for (int kk = 0; kk < nr; ++kk) {
            int st = (int)sb[lr][kk], en = (int)eb[lr][kk];
            int lo = max(st - l * 32, 0), hi = min(en - l * 32, 31);
            u32 mask = 0;
            if (lo <= hi)
                mask = ((hi == 31) ? 0xFFFFFFFFu : ((1u << (hi + 1)) - 1u)) & ~((1u << lo) - 1u);
            int any = __any((tK & mask) != 0);
            txtm |= (any ? 1u : 0u) << kk;
        }
        if (l < nr)
            rec[lr * RPR + l] = sb[lr][l] | (eb[lr][l] << 11) | (((txtm >> l) & 1u) << 22);
    }
    __syncthreads();

    // ---- Phase 3: vertical merges (7 row pairs, two-pointer, all LDS) ----
    if (t < SH - 1) {
        int na = nper[t], nb = nper[t + 1];
        int i = 0, j = 0;
        while (i < na && j < nb) {
            u32 ra = rec[t * RPR + i], rb = rec[(t + 1) * RPR + j];
            int sa = ra & 2047, ea = (ra >> 11) & 2047;
            int sb2 = rb & 2047, eb2 = (rb >> 11) & 2047;
            if (sa <= eb2 && sb2 <= ea) lmerge(lab, t * RPR + i, (t + 1) * RPR + j);
            if (ea <= eb2) ++i; else ++j;
        }
    }
    __syncthreads();

    // ---- Phase 4: jump compression ----
    #pragma unroll
    for (int pass = 0; pass < 5; ++pass) {
        if (t < SLOTS) {
            int p = lab[t], g = lab[p];
            if (g != p) lab[t] = g;
        }
        __syncthreads();
    }

    // ---- Phase 5: fold runs into strip-root accumulators (LDS atomics) ----
    int occ = (t < SLOTS) && ((t & (RPR - 1)) < nper[t >> 5]);
    if (occ) {
        u32 rc_ = rec[t];
        int st_ = rc_ & 2047, en_ = (rc_ >> 11) & 2047, tb = (int)((rc_ >> 22) & 1u);
        int r = rbase + (t >> 5);
        int root = lab[t];
        atomicMax(&a0[root], 2047 - r);
        atomicMax(&a1[root], r + 1);
        atomicMax(&a2[root], 2048 - st_);
        atomicMax(&a3[root], en_ + 1);
        if (tb) atomicOr(&atx[root], 1);
    }
    __syncthreads();

    // ---- Phase 6: allocate global node ids, write root records (stride 8) ---
    int flag = occ && (lab[t] == t);
    u64 bmask = __ballot(flag);
    int lanepfx = __popcll(bmask & ((1ull << l) - 1ull));
    if (l == 0) wtot[wv] = __popcll(bmask);
    __syncthreads();
    if (t == 0) {
        int s = 0;
        for (int w2 = 0; w2 < 8; ++w2) { woff[w2] = s; s += wtot[w2]; }
        sBase = atomicAdd(&ctrs[1], s);
    }
    __syncthreads();
    if (flag) {
        int node = sBase + woff[wv] + lanepfx;
        if (node < NCAP) {
            nodemap[t] = node;
            int g = node * 8;
            int r = rbase + (t >> 5);
            groots[g + 0] = a0[t];
            groots[g + 1] = a1[t];
            groots[g + 2] = a2[t];
            groots[g + 3] = a3[t];
            groots[g + 4] = atx[t];
            groots[g + 5] = (r << WSHIFT) | (int)(rec[t] & 2047);
        }
    }
    __syncthreads();

    // ---- Phase 7: emit boundary runs: packed contiguous + full fallback -----
    if (t < SLOTS) {
        int lr = t >> 5, k = t & (RPR - 1);
        if ((lr == 0 || lr == SH - 1) && k < nper[lr]) {
            int side = (lr == 0) ? 0 : 1;
            int id = nodemap[lab[t]];
            if (k < BSLOT)
                bpack[(strip * 2 + side) * BSLOT + k] =
                    (u64)rec[t] | ((u64)(u32)(id + 1) << 32);
            int o = (strip * 2 + side) * RPR + k;
            brun_se[o] = rec[t];
            brun_id[o] = id;
        }
    }
    if (t == 0) {
        bcnt[strip * 2 + 0] = nper[0];
        bcnt[strip * 2 + 1] = nper[SH - 1];
    }
    __syncthreads();

    // ---- last-block election: release fence + ACQ_REL RMW -------------------
    if (t == 0) {
        __threadfence();
        int old = __hip_atomic_fetch_add(&ctrs[0], 1, __ATOMIC_ACQ_REL,
                                         __HIP_MEMORY_SCOPE_AGENT);
        sLast = (old == NS - 1);
    }
    __syncthreads();
    if (!sLast) return;

    // ================= FINAL PHASE (last block; plain pipelined loads) =======
    int ncnt = min(ctrs[1], NCAP);
    for (int n = t; n < ncnt; n += 512) {
        flab[n] = n; f0[n] = 0; f1[n] = 0; f2[n] = 0; f3[n] = 0;
        ftx2[n] = 0; fpix[n] = INT_MAX;
    }
    for (int s = t; s < NS * 2; s += 512) sbc[s] = bcnt[s];
    #pragma unroll
    for (int u = t; u < NS * 2 * BSLOT; u += 512) sbpk[u] = bpack[u];
    __syncthreads();

    // joins: strip b last row vs strip b+1 first row
    if (t < NS - 1) {
        int A = t * 2 + 1, B = (t + 1) * 2;
        int na = sbc[A], nb = sbc[B];
        if (na <= BSLOT && nb <= BSLOT) {
            int i = 0, j = 0;
            while (i < na && j < nb) {
                u64 pa = sbpk[A * BSLOT + i], pb = sbpk[B * BSLOT + j];
                u32 ra = (u32)pa, rb = (u32)pb;
                int sa = ra & 2047, ea = (ra >> 11) & 2047;
                int sb2 = rb & 2047, eb2 = (rb >> 11) & 2047;
                if (sa <= eb2 && sb2 <= ea) {
                    int ia = (int)(pa >> 32) - 1, ib = (int)(pb >> 32) - 1;
                    if (ia >= 0 && ib >= 0) lmerge(flab, ia, ib);
                }
                if (ea <= eb2) ++i; else ++j;
            }
        } else {   // rare fallback: full arrays via agent-scope loads
            int i = 0, j = 0;
            while (i < na && j < nb) {
                u32 ra = GLD(&brun_se[A * RPR + i]), rb = GLD(&brun_se[B * RPR + j]);
                int sa = ra & 2047, ea = (ra >> 11) & 2047;
                int sb2 = rb & 2047, eb2 = (rb >> 11) & 2047;
                if (sa <= eb2 && sb2 <= ea) {
                    int ia = GLD(&brun_id[A * RPR + i]), ib = GLD(&brun_id[B * RPR + j]);
                    if (ia >= 0 && ib >= 0) lmerge(flab, ia, ib);
                }
                if (ea <= eb2) ++i; else ++j;
            }
        }
    }
    __syncthreads();

    #pragma unroll
    for (int pass = 0; pass < 5; ++pass) {     // jump compression
        for (int n = t; n < ncnt; n += 512) {
            int p = flab[n], g = flab[p];
            if (g != p) flab[n] = g;
        }
        __syncthreads();
    }

    // fold root records: two dwordx4 plain loads per node, LDS atomics
    for (int n = t; n < ncnt; n += 512) {
        int R = flab[n];
        v4i lo = *(const v4i*)&groots[n * 8];
        v4i hi = *(const v4i*)&groots[n * 8 + 4];
        atomicMax(&f0[R], lo.x);
        atomicMax(&f1[R], lo.y);
        atomicMax(&f2[R], lo.z);
        atomicMax(&f3[R], lo.w);
        if (hi.x) atomicOr(&ftx2[R], 1);
        atomicMin(&fpix[R], hi.y);
    }
    __syncthreads();

    // emit valid final roots into the k_flags-zeroed d_out
    for (int n = t; n < ncnt; n += 512) {
        if (flab[n] == n) {
            int ym = 2047 - f0[n], yx = f1[n] - 1;
            int xm = 2048 - f2[n], xx = f3[n] - 1;
            int h = yx - ym, w = xx - xm;
            if (h > 4 && w > 4 && ftx2[n]) {
                int p = fpix[n];
                v4i bb = {ym, xm, h, w};
                obb[p] = bb;
                oval[p] = 1;
            }
        }
    }
}

extern "C" void kernel_launch(void* const* d_in, const int* in_sizes, int n_in,
                              void* d_out, int out_size, void* d_ws, size_t ws_size,
                              hipStream_t stream) {
    const float* x = (const float*)d_in[0];

    // ws layout (alignment: groots 16B, bpack 8B)
    u32* combp   = (u32*)d_ws;                     // NPIX/32 words
    u32* textp   = combp + NPIX / 32;              // NPIX/32
    int* groots  = (int*)(textp + NPIX / 32);      // NCAP*8 (16B-aligned)
    u64* bpack   = (u64*)(groots + NCAP * 8);      // NS*2*BSLOT (8B-aligned)
    u32* brun_se = (u32*)(bpack + NS * 2 * BSLOT); // NS*2*RPR
    int* brun_id = (int*)(brun_se + NS * 2 * RPR); // NS*2*RPR
    int* bcnt    = brun_id + NS * 2 * RPR;         // NS*2
    int* ctrs    = bcnt + NS * 2;                  // [0]=done [1]=gcnt

    int* obb  = (int*)d_out;
    int* oval = obb + (size_t)NPIX * 4;

    k_flags<<<NPIX / 4 / 256, 256, 0, stream>>>((const float4*)x, (u64*)combp,
                                                (u64*)textp, (v4i*)d_out, ctrs);
    k_stripf<<<NS, 512, 0, stream>>>(combp, textp, brun_se, brun_id, bpack,
                                     bcnt, groots, ctrs, (v4i*)obb, oval);
}